// Round 6
// baseline (253.124 us; speedup 1.0000x reference)
//
#include <hip/hip_runtime.h>

#define BB 128
#define DD 8732
#define MM 32
#define CC 21

constexpr int K1_PR  = 4;                               // priors per thread (R2: occupancy fix)
constexpr int K1_CH  = 256 * K1_PR;                     // 1024 priors per block
constexpr int K1_NCH = (DD + K1_CH - 1) / K1_CH;        // 9 chunks -> 1152 blocks
constexpr int K2_CELLS = 256;
constexpr int K2_NBLK  = (DD + K2_CELLS - 1) / K2_CELLS; // 35 -> 4480 blocks
constexpr int K2B_PER  = (DD + 63) / 64;                 // 137 keys per lane (wave/row)
constexpr int OVW      = (DD + 31) / 32;                 // override bitmap words

// ---- workspace layout (bytes) ----
// R1 lesson: every atomic target on its own cache line.
constexpr size_t WS_DPG    = 0;                          // B*M u64 atomicMax keys (32768 B)
constexpr size_t WS_ROW    = 32768;                      // B rows * 64 B: [0]=conf f32, [1]=loc f32, [2]=npos i32
constexpr int    ROW_STRIDE = 16;                        // floats per row slot (64 B)
constexpr size_t WS_GSUM   = 40960;                      // f32, own line
constexpr size_t WS_GNPOS  = 41088;                      // i32, own line
constexpr size_t WS_DONE   = 41216;                      // u32, own line
constexpr size_t WS_ZERO_BYTES = 41344;                  // memset region
constexpr size_t WS_PACKED = 41472;                      // B*D u32 (lab<<8|bm)
constexpr size_t WS_CENEG  = WS_PACKED + (size_t)BB * DD * 4; // B*D f32

typedef float f32x4a4 __attribute__((ext_vector_type(4), aligned(4)));

__device__ __forceinline__ float wave_sum_f(float v) {
#pragma unroll
  for (int o = 32; o > 0; o >>= 1) v += __shfl_xor(v, o, 64);
  return v;
}
__device__ __forceinline__ int wave_sum_i(int v) {
#pragma unroll
  for (int o = 32; o > 0; o >>= 1) v += __shfl_xor(v, o, 64);
  return v;
}

// ---------------- K1: matching ----------------
__global__ __launch_bounds__(256) void k1_match(
    const float* __restrict__ gt_boxes, const int* __restrict__ gt_labels,
    const float* __restrict__ dboxes,
    unsigned int* __restrict__ packed, unsigned long long* __restrict__ dpg) {
  __shared__ float s_gx1[MM], s_gy1[MM], s_gx2[MM], s_gy2[MM], s_ga[MM];
  __shared__ int s_gl[MM];
  __shared__ unsigned long long s_pm[MM * 4];

  const int b = blockIdx.y;
  const int tid = threadIdx.x;
  if (tid < MM) {
    const float* g = gt_boxes + ((size_t)b * MM + tid) * 4;
    const float x1 = g[0], y1 = g[1], x2 = g[2], y2 = g[3];
    s_gx1[tid] = x1; s_gy1[tid] = y1; s_gx2[tid] = x2; s_gy2[tid] = y2;
    s_ga[tid] = __fmul_rn(__fsub_rn(x2, x1), __fsub_rn(y2, y1));
    s_gl[tid] = gt_labels[b * MM + tid];
  }
  __syncthreads();

  float px1[K1_PR], py1[K1_PR], px2[K1_PR], py2[K1_PR], pa[K1_PR];
  int dd[K1_PR];
  const int dbase = blockIdx.x * K1_CH + tid;
#pragma unroll
  for (int i = 0; i < K1_PR; ++i) {
    const int d = dbase + i * 256;
    if (d < DD) {
      const float4 p = *(const float4*)(dboxes + (size_t)d * 4);
      const float hw = __fmul_rn(p.z, 0.5f), hh = __fmul_rn(p.w, 0.5f);
      px1[i] = __fsub_rn(p.x, hw); py1[i] = __fsub_rn(p.y, hh);
      px2[i] = __fadd_rn(p.x, hw); py2[i] = __fadd_rn(p.y, hh);
      pa[i] = __fmul_rn(__fsub_rn(px2[i], px1[i]), __fsub_rn(py2[i], py1[i]));
      dd[i] = d;
    } else {  // pad: iou=0, can never win (val 0, huge d)
      px1[i] = 3e9f; py1[i] = 3e9f; px2[i] = 3e9f; py2[i] = 3e9f; pa[i] = 1.0f;
      dd[i] = 0x7FFFFFFF;
    }
  }

  float vb[K1_PR]; int mb[K1_PR];
#pragma unroll
  for (int i = 0; i < K1_PR; ++i) { vb[i] = -1.0f; mb[i] = 0; }

  const int lane = tid & 63, wid = tid >> 6;
  for (int m = 0; m < MM; ++m) {
    const float gx1 = s_gx1[m], gy1 = s_gy1[m], gx2 = s_gx2[m], gy2 = s_gy2[m];
    const float ga = s_ga[m];
    float mv = -1.0f; int md = 0x7FFFFFFF;
#pragma unroll
    for (int i = 0; i < K1_PR; ++i) {
      // exact (non-contracted) f32 to match numpy bit-for-bit
      const float w = fmaxf(0.0f, __fsub_rn(fminf(gx2, px2[i]), fmaxf(gx1, px1[i])));
      const float h = fmaxf(0.0f, __fsub_rn(fminf(gy2, py2[i]), fmaxf(gy1, py1[i])));
      const float inter = __fmul_rn(w, h);
      const float den = __fsub_rn(__fadd_rn(ga, pa[i]), inter);
      const float val = __fdiv_rn(inter, den);
      if (val > vb[i]) { vb[i] = val; mb[i] = m; }   // strict >: first m wins
      if (val > mv) { mv = val; md = dd[i]; }        // d ascending: first d wins
    }
    // f32 max + min-d over tied lanes; skip d-reduce when wave max IoU is 0.
    float wm = mv;
#pragma unroll
    for (int o = 32; o > 0; o >>= 1) wm = fmaxf(wm, __shfl_xor(wm, o, 64));
    unsigned long long key = 0ull;
    if (wm > 0.0f) {
      int cd = (mv == wm) ? md : 0x7FFFFFFF;
#pragma unroll
      for (int o = 32; o > 0; o >>= 1) cd = min(cd, __shfl_xor(cd, o, 64));
      key = (((unsigned long long)__float_as_uint(wm)) << 32) |
            (unsigned long long)(0xFFFFFFFFu - (unsigned)cd);
    }
    if (lane == 0) s_pm[m * 4 + wid] = key;
  }
  __syncthreads();
  if (tid < MM) {
    unsigned long long k0 = s_pm[tid * 4 + 0];
    if (s_pm[tid * 4 + 1] > k0) k0 = s_pm[tid * 4 + 1];
    if (s_pm[tid * 4 + 2] > k0) k0 = s_pm[tid * 4 + 2];
    if (s_pm[tid * 4 + 3] > k0) k0 = s_pm[tid * 4 + 3];
    if (k0) atomicMax(&dpg[b * MM + tid], k0);
  }
#pragma unroll
  for (int i = 0; i < K1_PR; ++i) {
    if (dd[i] < DD) {
      const int lab = (vb[i] < 0.5f) ? 0 : s_gl[mb[i]];
      packed[(size_t)b * DD + dd[i]] = ((unsigned)lab << 8) | (unsigned)mb[i];
    }
  }
}

// ------- K2a: CE + loc + n_pos. R6: direct global loads, no cls LDS --------
__global__ __launch_bounds__(256) void k2a_ce(
    const float* __restrict__ loc_pred, const float* __restrict__ cls_pred,
    const float* __restrict__ gt_boxes, const int* __restrict__ gt_labels,
    const float* __restrict__ dboxes, const unsigned int* __restrict__ packed,
    const unsigned long long* __restrict__ dpg, float* __restrict__ ce_neg,
    float* __restrict__ rowacc) {
  __shared__ int s_dstar[MM], s_lab[MM];
  __shared__ float4 s_gt[MM];
  __shared__ unsigned s_ov[OVW];              // force-match bitmap
  __shared__ float s_rf[4], s_rl[4];
  __shared__ int s_ri[4];

  const int b = blockIdx.y;
  const int d0 = blockIdx.x * K2_CELLS;
  const int tid = threadIdx.x;

  for (int i = tid; i < OVW; i += 256) s_ov[i] = 0;
  int my_ds = -1;
  if (tid < MM) {
    my_ds = (int)(0xFFFFFFFFu - (unsigned)(dpg[b * MM + tid] & 0xFFFFFFFFull));
    s_dstar[tid] = my_ds;
    s_lab[tid] = gt_labels[b * MM + tid];
    s_gt[tid] = *(const float4*)(gt_boxes + ((size_t)b * MM + tid) * 4);
  }
  __syncthreads();                             // s_ov zero-init complete
  if (tid < MM && (unsigned)my_ds < DD)
    atomicOr(&s_ov[my_ds >> 5], 1u << (my_ds & 31));
  __syncthreads();                             // bitmap complete

  float ce_pos = 0.0f, sl1 = 0.0f; int posc = 0;
  const int d = d0 + tid;
  if (d < DD) {
    const unsigned p = packed[(size_t)b * DD + d];
    int bm = (int)(p & 255u), lab = (int)(p >> 8);
    if ((s_ov[d >> 5] >> (d & 31)) & 1u) {     // rare: ~32/8732 cells per row
#pragma unroll
      for (int m = 0; m < MM; ++m)  // ascending m = last wins (ref .at[].set)
        if (s_dstar[m] == d) { bm = m; lab = s_lab[m]; }
    }
    // Direct register CE: thread's 21 floats are contiguous in global.
    const float* x = cls_pred + ((size_t)b * DD + d) * CC;
    float xv[21];
    {
      const f32x4a4 v0 = *(const f32x4a4*)(x);
      const f32x4a4 v1 = *(const f32x4a4*)(x + 4);
      const f32x4a4 v2 = *(const f32x4a4*)(x + 8);
      const f32x4a4 v3 = *(const f32x4a4*)(x + 12);
      const f32x4a4 v4 = *(const f32x4a4*)(x + 16);
      xv[0]=v0.x; xv[1]=v0.y; xv[2]=v0.z; xv[3]=v0.w;
      xv[4]=v1.x; xv[5]=v1.y; xv[6]=v1.z; xv[7]=v1.w;
      xv[8]=v2.x; xv[9]=v2.y; xv[10]=v2.z; xv[11]=v2.w;
      xv[12]=v3.x; xv[13]=v3.y; xv[14]=v3.z; xv[15]=v3.w;
      xv[16]=v4.x; xv[17]=v4.y; xv[18]=v4.z; xv[19]=v4.w;
      xv[20]=x[20];
    }
    const float xl = x[lab];                   // L1 hit (line already resident)
    float mx = xv[0];
#pragma unroll
    for (int c = 1; c < CC; ++c) mx = fmaxf(mx, xv[c]);
    float se = 0.0f;
#pragma unroll
    for (int c = 0; c < CC; ++c) se = __fadd_rn(se, __expf(__fsub_rn(xv[c], mx)));
    const float ce = __fsub_rn(__fadd_rn(mx, __logf(se)), xl);
    const bool pos = lab > 0;
    ce_neg[(size_t)b * DD + d] = pos ? -1.0f : ce;
    if (pos) {
      posc = 1; ce_pos = ce;
      const float4 lp = *(const float4*)(loc_pred + ((size_t)b * DD + d) * 4);
      const float4 pr = *(const float4*)(dboxes + (size_t)d * 4);  // cx cy w h
      const float4 g = s_gt[bm];
      const float gcx = __fmul_rn(__fadd_rn(g.x, g.z), 0.5f);
      const float gcy = __fmul_rn(__fadd_rn(g.y, g.w), 0.5f);
      const float gw = __fsub_rn(g.z, g.x), gh = __fsub_rn(g.w, g.y);
      const float t0 = __fdiv_rn(__fsub_rn(gcx, pr.x), __fdiv_rn(pr.z, 10.0f));
      const float t1 = __fdiv_rn(__fsub_rn(gcy, pr.y), __fdiv_rn(pr.w, 10.0f));
      const float t2 = __fmul_rn(__logf(__fdiv_rn(gw, pr.z)), 5.0f);
      const float t3 = __fmul_rn(__logf(__fdiv_rn(gh, pr.w)), 5.0f);
      float dv, ad;
      dv = __fsub_rn(lp.x, t0); ad = fabsf(dv);
      sl1 += (ad < 1.0f) ? __fmul_rn(0.5f, __fmul_rn(dv, dv)) : __fsub_rn(ad, 0.5f);
      dv = __fsub_rn(lp.y, t1); ad = fabsf(dv);
      sl1 += (ad < 1.0f) ? __fmul_rn(0.5f, __fmul_rn(dv, dv)) : __fsub_rn(ad, 0.5f);
      dv = __fsub_rn(lp.z, t2); ad = fabsf(dv);
      sl1 += (ad < 1.0f) ? __fmul_rn(0.5f, __fmul_rn(dv, dv)) : __fsub_rn(ad, 0.5f);
      dv = __fsub_rn(lp.w, t3); ad = fabsf(dv);
      sl1 += (ad < 1.0f) ? __fmul_rn(0.5f, __fmul_rn(dv, dv)) : __fsub_rn(ad, 0.5f);
    }
  }
  const float cs = wave_sum_f(ce_pos);
  const float ls = wave_sum_f(sl1);
  const int ps = wave_sum_i(posc);
  const int lane = tid & 63, wid = tid >> 6;
  if (lane == 0) { s_rf[wid] = cs; s_rl[wid] = ls; s_ri[wid] = ps; }
  __syncthreads();
  if (tid == 0) {
    const float c = s_rf[0] + s_rf[1] + s_rf[2] + s_rf[3];
    const float l = s_rl[0] + s_rl[1] + s_rl[2] + s_rl[3];
    const int p = s_ri[0] + s_ri[1] + s_ri[2] + s_ri[3];
    float* row = rowacc + b * ROW_STRIDE;   // 64-B private slot for row b
    atomicAdd(&row[0], c);
    atomicAdd(&row[1], l);
    if (p) atomicAdd((int*)&row[2], p);
  }
}

// ---- K2b: one WAVE per row, keys in VGPRs, zero barriers (R6) -------------
__global__ __launch_bounds__(64) void k2b_topk(
    const float* __restrict__ ce_neg, const float* __restrict__ rowacc,
    float* __restrict__ gsum, int* __restrict__ gnpos,
    unsigned int* __restrict__ done, float* __restrict__ out) {
  const int b = blockIdx.x;
  const int lane = threadIdx.x;
  const float* row = rowacc + b * ROW_STRIDE;
  const int np = ((const int*)row)[2];
  const int k = min(3 * np, DD - np);

  unsigned key[K2B_PER];                      // 137 VGPRs, coalesced loads
#pragma unroll
  for (int i = 0; i < K2B_PER; ++i) {
    const int d = lane + i * 64;
    if (d < DD) {
      const unsigned u = __float_as_uint(ce_neg[(size_t)b * DD + d]);
      key[i] = (u & 0x80000000u) ? ~u : (u | 0x80000000u);  // sortable key
    } else key[i] = 0u;
  }

  float topk_sum = 0.0f;
  if (k > 0) {
    // All negative keys have bit31 set and k <= #negatives, so the threshold
    // key has bit31 too: start at T=0x80000000, search remaining 31 bits.
    unsigned T = 0x80000000u;
    for (int bit = 30; bit >= 0; --bit) {
      const unsigned cand = T | (1u << bit);
      int c = 0;
#pragma unroll
      for (int i = 0; i < K2B_PER; ++i) c += (key[i] >= cand) ? 1 : 0;
      c = wave_sum_i(c);                      // uniform across lanes
      if (c >= k) T = cand;
    }
    int c = 0; float s = 0.0f;
#pragma unroll
    for (int i = 0; i < K2B_PER; ++i) {
      if (key[i] > T) { c += 1; s += __uint_as_float(key[i] ^ 0x80000000u); }
    }
    c = wave_sum_i(c); s = wave_sum_f(s);
    const float vT = __uint_as_float(T ^ 0x80000000u);
    topk_sum = s + (float)(k - c) * vT;       // uniform
  }
  if (lane == 0) {
    // one atomic per row into dedicated lines (128-way total)
    atomicAdd(gsum, row[0] + row[1] + topk_sum);
    atomicAdd(gnpos, np);
    __threadfence();
    const unsigned old = atomicAdd(done, 1u);
    if (old == BB - 1) {  // last row finalizes the scalar
      const float total = atomicAdd(gsum, 0.0f);
      const int npt = atomicAdd(gnpos, 0);
      const float nt = (float)((npt > 0) ? npt : 1);
      out[0] = __fdiv_rn(total, nt);
    }
  }
}

extern "C" void kernel_launch(void* const* d_in, const int* in_sizes, int n_in,
                              void* d_out, int out_size, void* d_ws, size_t ws_size,
                              hipStream_t stream) {
  const float* loc_pred = (const float*)d_in[0];
  const float* cls_pred = (const float*)d_in[1];
  const float* gt_boxes = (const float*)d_in[2];
  const int* gt_labels = (const int*)d_in[3];
  const float* dboxes = (const float*)d_in[4];

  char* ws = (char*)d_ws;
  unsigned long long* dpg = (unsigned long long*)(ws + WS_DPG);
  float* rowacc = (float*)(ws + WS_ROW);
  float* gsum = (float*)(ws + WS_GSUM);
  int* gnpos = (int*)(ws + WS_GNPOS);
  unsigned int* done = (unsigned int*)(ws + WS_DONE);
  unsigned int* packed = (unsigned int*)(ws + WS_PACKED);
  float* ce_neg = (float*)(ws + WS_CENEG);

  hipMemsetAsync(ws, 0, WS_ZERO_BYTES, stream);

  k1_match<<<dim3(K1_NCH, BB), 256, 0, stream>>>(gt_boxes, gt_labels, dboxes,
                                                 packed, dpg);
  k2a_ce<<<dim3(K2_NBLK, BB), 256, 0, stream>>>(loc_pred, cls_pred, gt_boxes,
                                                gt_labels, dboxes, packed, dpg,
                                                ce_neg, rowacc);
  k2b_topk<<<BB, 64, 0, stream>>>(ce_neg, rowacc, gsum, gnpos, done,
                                  (float*)d_out);
}

// Round 7
// 234.946 us; speedup vs baseline: 1.0774x; 1.0774x over previous
//
#include <hip/hip_runtime.h>

#define BB 128
#define DD 8732
#define MM 32
#define CC 21

constexpr int K1_PR  = 4;                               // priors per thread (R2: occupancy fix)
constexpr int K1_CH  = 256 * K1_PR;                     // 1024 priors per block
constexpr int K1_NCH = (DD + K1_CH - 1) / K1_CH;        // 9 chunks -> 1152 blocks
constexpr int K2_CELLS = 256;
constexpr int K2_NBLK  = (DD + K2_CELLS - 1) / K2_CELLS; // 35 -> 4480 blocks
constexpr int K2B_T    = 1024;                           // k2b block size (R5-measured variant)
constexpr int K2B_PER  = (DD + K2B_T - 1) / K2B_T;       // 9 keys per thread
constexpr int K2B_W    = K2B_T / 64;                     // 16 waves
constexpr int OVW      = (DD + 31) / 32;                 // override bitmap words

// ---- workspace layout (bytes) ----
// R1 lesson: every atomic target on its own cache line.
constexpr size_t WS_DPG    = 0;                          // B*M u64 atomicMax keys (32768 B)
constexpr size_t WS_ROW    = 32768;                      // B rows * 64 B: [0]=conf f32, [1]=loc f32, [2]=npos i32
constexpr int    ROW_STRIDE = 16;                        // floats per row slot (64 B)
constexpr size_t WS_GSUM   = 40960;                      // f32, own line
constexpr size_t WS_GNPOS  = 41088;                      // i32, own line
constexpr size_t WS_DONE   = 41216;                      // u32, own line
constexpr size_t WS_ZERO_BYTES = 41344;                  // memset region
constexpr size_t WS_PACKED = 41472;                      // B*D u32 (lab<<8|bm)
constexpr size_t WS_CEKEY  = WS_PACKED + (size_t)BB * DD * 4; // B*D u32 sortable keys

__device__ __forceinline__ float wave_sum_f(float v) {
#pragma unroll
  for (int o = 32; o > 0; o >>= 1) v += __shfl_xor(v, o, 64);
  return v;
}
__device__ __forceinline__ int wave_sum_i(int v) {
#pragma unroll
  for (int o = 32; o > 0; o >>= 1) v += __shfl_xor(v, o, 64);
  return v;
}

// ---------------- K1: matching ----------------
// R7: __fdividef (rcp+mul) replaces exact __fdiv_rn — 128 divs/thread was
// the VALU hot spot. <=2.5 ulp quotient error can flip argmax/threshold only
// on ~1e-7-wide ties (~10 events over 35.8M cmps, ~3e-3 loss delta each).
__global__ __launch_bounds__(256) void k1_match(
    const float* __restrict__ gt_boxes, const int* __restrict__ gt_labels,
    const float* __restrict__ dboxes,
    unsigned int* __restrict__ packed, unsigned long long* __restrict__ dpg) {
  __shared__ float s_gx1[MM], s_gy1[MM], s_gx2[MM], s_gy2[MM], s_ga[MM];
  __shared__ int s_gl[MM];
  __shared__ unsigned long long s_pm[MM * 4];

  const int b = blockIdx.y;
  const int tid = threadIdx.x;
  if (tid < MM) {
    const float* g = gt_boxes + ((size_t)b * MM + tid) * 4;
    const float x1 = g[0], y1 = g[1], x2 = g[2], y2 = g[3];
    s_gx1[tid] = x1; s_gy1[tid] = y1; s_gx2[tid] = x2; s_gy2[tid] = y2;
    s_ga[tid] = __fmul_rn(__fsub_rn(x2, x1), __fsub_rn(y2, y1));
    s_gl[tid] = gt_labels[b * MM + tid];
  }
  __syncthreads();

  float px1[K1_PR], py1[K1_PR], px2[K1_PR], py2[K1_PR], pa[K1_PR];
  int dd[K1_PR];
  const int dbase = blockIdx.x * K1_CH + tid;
#pragma unroll
  for (int i = 0; i < K1_PR; ++i) {
    const int d = dbase + i * 256;
    if (d < DD) {
      const float4 p = *(const float4*)(dboxes + (size_t)d * 4);
      const float hw = __fmul_rn(p.z, 0.5f), hh = __fmul_rn(p.w, 0.5f);
      px1[i] = __fsub_rn(p.x, hw); py1[i] = __fsub_rn(p.y, hh);
      px2[i] = __fadd_rn(p.x, hw); py2[i] = __fadd_rn(p.y, hh);
      pa[i] = __fmul_rn(__fsub_rn(px2[i], px1[i]), __fsub_rn(py2[i], py1[i]));
      dd[i] = d;
    } else {  // pad: iou=0, can never win (val 0, huge d)
      px1[i] = 3e9f; py1[i] = 3e9f; px2[i] = 3e9f; py2[i] = 3e9f; pa[i] = 1.0f;
      dd[i] = 0x7FFFFFFF;
    }
  }

  float vb[K1_PR]; int mb[K1_PR];
#pragma unroll
  for (int i = 0; i < K1_PR; ++i) { vb[i] = -1.0f; mb[i] = 0; }

  const int lane = tid & 63, wid = tid >> 6;
  for (int m = 0; m < MM; ++m) {
    const float gx1 = s_gx1[m], gy1 = s_gy1[m], gx2 = s_gx2[m], gy2 = s_gy2[m];
    const float ga = s_ga[m];
    float mv = -1.0f; int md = 0x7FFFFFFF;
#pragma unroll
    for (int i = 0; i < K1_PR; ++i) {
      const float w = fmaxf(0.0f, __fsub_rn(fminf(gx2, px2[i]), fmaxf(gx1, px1[i])));
      const float h = fmaxf(0.0f, __fsub_rn(fminf(gy2, py2[i]), fmaxf(gy1, py1[i])));
      const float inter = __fmul_rn(w, h);
      const float den = __fsub_rn(__fadd_rn(ga, pa[i]), inter);
      const float val = __fdividef(inter, den);      // fast rcp-based div
      if (val > vb[i]) { vb[i] = val; mb[i] = m; }   // strict >: first m wins
      if (val > mv) { mv = val; md = dd[i]; }        // d ascending: first d wins
    }
    // f32 max + min-d over tied lanes; skip d-reduce when wave max IoU is 0.
    float wm = mv;
#pragma unroll
    for (int o = 32; o > 0; o >>= 1) wm = fmaxf(wm, __shfl_xor(wm, o, 64));
    unsigned long long key = 0ull;
    if (wm > 0.0f) {
      int cd = (mv == wm) ? md : 0x7FFFFFFF;
#pragma unroll
      for (int o = 32; o > 0; o >>= 1) cd = min(cd, __shfl_xor(cd, o, 64));
      key = (((unsigned long long)__float_as_uint(wm)) << 32) |
            (unsigned long long)(0xFFFFFFFFu - (unsigned)cd);
    }
    if (lane == 0) s_pm[m * 4 + wid] = key;
  }
  __syncthreads();
  if (tid < MM) {
    unsigned long long k0 = s_pm[tid * 4 + 0];
    if (s_pm[tid * 4 + 1] > k0) k0 = s_pm[tid * 4 + 1];
    if (s_pm[tid * 4 + 2] > k0) k0 = s_pm[tid * 4 + 2];
    if (s_pm[tid * 4 + 3] > k0) k0 = s_pm[tid * 4 + 3];
    if (k0) atomicMax(&dpg[b * MM + tid], k0);
  }
#pragma unroll
  for (int i = 0; i < K1_PR; ++i) {
    if (dd[i] < DD) {
      const int lab = (vb[i] < 0.5f) ? 0 : s_gl[mb[i]];
      packed[(size_t)b * DD + dd[i]] = ((unsigned)lab << 8) | (unsigned)mb[i];
    }
  }
}

// ------- K2a: CE + loc + n_pos (R5-measured LDS-staging variant) -----------
// R7: ce written pre-transformed as sortable u32 key (pos -> 0).
__global__ __launch_bounds__(256) void k2a_ce(
    const float* __restrict__ loc_pred, const float* __restrict__ cls_pred,
    const float* __restrict__ gt_boxes, const int* __restrict__ gt_labels,
    const float* __restrict__ dboxes, const unsigned int* __restrict__ packed,
    const unsigned long long* __restrict__ dpg, unsigned int* __restrict__ ce_key,
    float* __restrict__ rowacc) {
  __shared__ float s_cls[K2_CELLS * CC];
  __shared__ int s_dstar[MM], s_lab[MM];
  __shared__ float4 s_gt[MM];
  __shared__ unsigned s_ov[OVW];              // force-match bitmap
  __shared__ float s_rf[4], s_rl[4];
  __shared__ int s_ri[4];

  const int b = blockIdx.y;
  const int d0 = blockIdx.x * K2_CELLS;
  const int tid = threadIdx.x;
  const int ncell = min(K2_CELLS, DD - d0);
  const int nflt = ncell * CC;

  for (int i = tid; i < OVW; i += 256) s_ov[i] = 0;
  if (tid < MM) {
    s_dstar[tid] = (int)(0xFFFFFFFFu - (unsigned)(dpg[b * MM + tid] & 0xFFFFFFFFull));
    s_lab[tid] = gt_labels[b * MM + tid];
    s_gt[tid] = *(const float4*)(gt_boxes + ((size_t)b * MM + tid) * 4);
  }
  __syncthreads();                             // s_ov zero-init complete

  if (tid < MM) {
    const unsigned ds = (unsigned)s_dstar[tid];
    if (ds < DD) atomicOr(&s_ov[ds >> 5], 1u << (ds & 31));
  }
  const float* srcf = cls_pred + ((size_t)b * DD + d0) * CC;  // 16B-aligned
  const int nv4 = nflt >> 2;
  for (int i = tid; i < nv4; i += 256)
    ((float4*)s_cls)[i] = ((const float4*)srcf)[i];
  for (int i = (nv4 << 2) + tid; i < nflt; i += 256) s_cls[i] = srcf[i];
  __syncthreads();                             // staging + bitmap complete

  float ce_pos = 0.0f, sl1 = 0.0f; int posc = 0;
  if (tid < ncell) {
    const int d = d0 + tid;
    const unsigned p = packed[(size_t)b * DD + d];
    int bm = (int)(p & 255u), lab = (int)(p >> 8);
    if ((s_ov[d >> 5] >> (d & 31)) & 1u) {     // rare: ~32/8732 cells per row
#pragma unroll
      for (int m = 0; m < MM; ++m)  // ascending m = last wins (ref .at[].set)
        if (s_dstar[m] == d) { bm = m; lab = s_lab[m]; }
    }
    const float* x = &s_cls[tid * CC];         // stride 21 (odd): conflict-free
    float mx = x[0];
#pragma unroll
    for (int c = 1; c < CC; ++c) mx = fmaxf(mx, x[c]);
    float se = 0.0f;
#pragma unroll
    for (int c = 0; c < CC; ++c) se = __fadd_rn(se, __expf(__fsub_rn(x[c], mx)));
    const float ce = __fsub_rn(__fadd_rn(mx, __logf(se)), x[lab]);
    const bool pos = lab > 0;
    // sortable key: ce >= 0 always (lse >= x[lab]); positives excluded via 0
    ce_key[(size_t)b * DD + d] = pos ? 0u : (__float_as_uint(ce) | 0x80000000u);
    if (pos) {
      posc = 1; ce_pos = ce;
      const float4 lp = *(const float4*)(loc_pred + ((size_t)b * DD + d) * 4);
      const float4 pr = *(const float4*)(dboxes + (size_t)d * 4);  // cx cy w h
      const float4 g = s_gt[bm];
      const float gcx = __fmul_rn(__fadd_rn(g.x, g.z), 0.5f);
      const float gcy = __fmul_rn(__fadd_rn(g.y, g.w), 0.5f);
      const float gw = __fsub_rn(g.z, g.x), gh = __fsub_rn(g.w, g.y);
      const float t0 = __fdiv_rn(__fsub_rn(gcx, pr.x), __fdiv_rn(pr.z, 10.0f));
      const float t1 = __fdiv_rn(__fsub_rn(gcy, pr.y), __fdiv_rn(pr.w, 10.0f));
      const float t2 = __fmul_rn(__logf(__fdiv_rn(gw, pr.z)), 5.0f);
      const float t3 = __fmul_rn(__logf(__fdiv_rn(gh, pr.w)), 5.0f);
      float dv, ad;
      dv = __fsub_rn(lp.x, t0); ad = fabsf(dv);
      sl1 += (ad < 1.0f) ? __fmul_rn(0.5f, __fmul_rn(dv, dv)) : __fsub_rn(ad, 0.5f);
      dv = __fsub_rn(lp.y, t1); ad = fabsf(dv);
      sl1 += (ad < 1.0f) ? __fmul_rn(0.5f, __fmul_rn(dv, dv)) : __fsub_rn(ad, 0.5f);
      dv = __fsub_rn(lp.z, t2); ad = fabsf(dv);
      sl1 += (ad < 1.0f) ? __fmul_rn(0.5f, __fmul_rn(dv, dv)) : __fsub_rn(ad, 0.5f);
      dv = __fsub_rn(lp.w, t3); ad = fabsf(dv);
      sl1 += (ad < 1.0f) ? __fmul_rn(0.5f, __fmul_rn(dv, dv)) : __fsub_rn(ad, 0.5f);
    }
  }
  const float cs = wave_sum_f(ce_pos);
  const float ls = wave_sum_f(sl1);
  const int ps = wave_sum_i(posc);
  const int lane = tid & 63, wid = tid >> 6;
  if (lane == 0) { s_rf[wid] = cs; s_rl[wid] = ls; s_ri[wid] = ps; }
  __syncthreads();
  if (tid == 0) {
    const float c = s_rf[0] + s_rf[1] + s_rf[2] + s_rf[3];
    const float l = s_rl[0] + s_rl[1] + s_rl[2] + s_rl[3];
    const int p = s_ri[0] + s_ri[1] + s_ri[2] + s_ri[3];
    float* row = rowacc + b * ROW_STRIDE;   // 64-B private slot for row b
    atomicAdd(&row[0], c);
    atomicAdd(&row[1], l);
    if (p) atomicAdd((int*)&row[2], p);
  }
}

// ---------------- K2b: per-row top-k negatives + final reduce ----------------
// R7: pre-keyed loads, 31 rounds (T starts at 0x80000000), parity-dbuf
// counts -> 1 barrier per round.
__global__ __launch_bounds__(K2B_T) void k2b_topk(
    const unsigned int* __restrict__ ce_key, const float* __restrict__ rowacc,
    float* __restrict__ gsum, int* __restrict__ gnpos,
    unsigned int* __restrict__ done, float* __restrict__ out) {
  __shared__ int s_bc[2][K2B_W];
  __shared__ int s_ri[K2B_W];
  __shared__ float s_rf[K2B_W];
  const int b = blockIdx.x;
  const int tid = threadIdx.x;
  const int lane = tid & 63, wid = tid >> 6;
  const float* row = rowacc + b * ROW_STRIDE;
  const int np = ((const int*)row)[2];
  const int k = min(3 * np, DD - np);

  unsigned key[K2B_PER];
#pragma unroll
  for (int i = 0; i < K2B_PER; ++i) {
    const int d = tid + i * K2B_T;
    key[i] = (d < DD) ? ce_key[(size_t)b * DD + d] : 0u;
  }

  float topk_sum = 0.0f;
  if (k > 0) {
    // All negative keys have bit31 set and k <= #negatives -> threshold does too.
    unsigned T = 0x80000000u;
    int par = 0;
    for (int bit = 30; bit >= 0; --bit) {
      const unsigned cand = T | (1u << bit);
      int c = 0;
#pragma unroll
      for (int i = 0; i < K2B_PER; ++i) c += (key[i] >= cand) ? 1 : 0;
      c = wave_sum_i(c);
      if (lane == 0) s_bc[par][wid] = c;
      __syncthreads();                        // read of par r precedes barrier
      int total = 0;                          // preceding write of par r+2
#pragma unroll
      for (int w = 0; w < K2B_W; ++w) total += s_bc[par][w];
      if (total >= k) T = cand;
      par ^= 1;
    }
    int c = 0; float s = 0.0f;
#pragma unroll
    for (int i = 0; i < K2B_PER; ++i) {
      if (key[i] > T) { c += 1; s += __uint_as_float(key[i] ^ 0x80000000u); }
    }
    c = wave_sum_i(c); s = wave_sum_f(s);
    if (lane == 0) { s_ri[wid] = c; s_rf[wid] = s; }
    __syncthreads();
    if (tid == 0) {
      int cg = 0; float sg = 0.0f;
#pragma unroll
      for (int w = 0; w < K2B_W; ++w) { cg += s_ri[w]; sg += s_rf[w]; }
      const float vT = __uint_as_float(T ^ 0x80000000u);
      topk_sum = sg + (float)(k - cg) * vT;
    }
  }
  if (tid == 0) {
    // one atomic per row into dedicated lines (128-way total)
    atomicAdd(gsum, row[0] + row[1] + topk_sum);
    atomicAdd(gnpos, np);
    __threadfence();
    const unsigned old = atomicAdd(done, 1u);
    if (old == BB - 1) {  // last row finalizes the scalar
      const float total = atomicAdd(gsum, 0.0f);
      const int npt = atomicAdd(gnpos, 0);
      const float nt = (float)((npt > 0) ? npt : 1);
      out[0] = __fdiv_rn(total, nt);
    }
  }
}

extern "C" void kernel_launch(void* const* d_in, const int* in_sizes, int n_in,
                              void* d_out, int out_size, void* d_ws, size_t ws_size,
                              hipStream_t stream) {
  const float* loc_pred = (const float*)d_in[0];
  const float* cls_pred = (const float*)d_in[1];
  const float* gt_boxes = (const float*)d_in[2];
  const int* gt_labels = (const int*)d_in[3];
  const float* dboxes = (const float*)d_in[4];

  char* ws = (char*)d_ws;
  unsigned long long* dpg = (unsigned long long*)(ws + WS_DPG);
  float* rowacc = (float*)(ws + WS_ROW);
  float* gsum = (float*)(ws + WS_GSUM);
  int* gnpos = (int*)(ws + WS_GNPOS);
  unsigned int* done = (unsigned int*)(ws + WS_DONE);
  unsigned int* packed = (unsigned int*)(ws + WS_PACKED);
  unsigned int* ce_key = (unsigned int*)(ws + WS_CEKEY);

  hipMemsetAsync(ws, 0, WS_ZERO_BYTES, stream);

  k1_match<<<dim3(K1_NCH, BB), 256, 0, stream>>>(gt_boxes, gt_labels, dboxes,
                                                 packed, dpg);
  k2a_ce<<<dim3(K2_NBLK, BB), 256, 0, stream>>>(loc_pred, cls_pred, gt_boxes,
                                                gt_labels, dboxes, packed, dpg,
                                                ce_key, rowacc);
  k2b_topk<<<BB, K2B_T, 0, stream>>>(ce_key, rowacc, gsum, gnpos, done,
                                     (float*)d_out);
}